// Round 1
// baseline (127.776 us; speedup 1.0000x reference)
//
#include <hip/hip_runtime.h>
#include <hip/hip_bf16.h>

#define F      128
#define NROWS  2048
#define MROWS  2048
#define BN     32          // n-rows per block (pair kernel)
#define BM     64          // m-cols per block
#define MT     (MROWS/BM)  // 32 m-tiles
#define LDP    132         // padded LDS row stride in floats: 16B-aligned, %32==4

__device__ __forceinline__ float elu_f(float x) {
    float e = __expf(x) - 1.0f;
    return x > 0.0f ? x : e;
}

// --- Kernel 1: A = embeds @ W1, B = base_embeds @ W1 -------------------------
// block = 256 threads = 2 rows; g = tid & 127
__global__ __launch_bounds__(256) void proj_kernel(
    const float* __restrict__ embeds, const float* __restrict__ base,
    const float* __restrict__ W1, float* __restrict__ A, float* __restrict__ Bo)
{
    const int tid = threadIdx.x;
    const int sub = tid >> 7;          // 0/1 row within block
    const int g   = tid & 127;
    const int row = blockIdx.x * 2 + sub;

    __shared__ float xs[2][F];
    {
        const float* src = (row < NROWS) ? &embeds[(size_t)row * F]
                                         : &base[(size_t)(row - NROWS) * F];
        xs[sub][g] = src[g];
    }
    __syncthreads();

    float acc = 0.0f;
#pragma unroll 8
    for (int f = 0; f < F; ++f)
        acc = fmaf(xs[sub][f], W1[f * F + g], acc);

    float* dst = (row < NROWS) ? &A[(size_t)row * F]
                               : &Bo[(size_t)(row - NROWS) * F];
    dst[g] = acc;
}

// --- Kernel 2: per-pair elu-dot, inverse-distance partial sums ---------------
// grid (NROWS/BN, MROWS/BM); 256 threads: n_local = tid>>3 (32), m covered by
// (tid&7) + 8*j, j=0..7. Deterministic (no atomics).
__global__ __launch_bounds__(256) void pair_kernel(
    const float* __restrict__ A, const float* __restrict__ Bp,
    const float* __restrict__ w2, const float* __restrict__ brew,
    float* __restrict__ partials)
{
    __shared__ float As[BN][LDP];
    __shared__ float Bs[BM][LDP];
    __shared__ float w2s[F];
    __shared__ float rs[BM];

    const int tid = threadIdx.x;
    const int nt  = blockIdx.x;
    const int mt  = blockIdx.y;

    // stage A-tile: 32 rows x 128 -> 1024 float4
    for (int i = tid; i < BN * (F / 4); i += 256) {
        const int r = i >> 5, c = (i & 31) * 4;
        const float4 v = *(const float4*)&A[(size_t)(nt * BN + r) * F + c];
        *(float4*)&As[r][c] = v;
    }
    // stage B-tile: 64 rows x 128 -> 2048 float4
    for (int i = tid; i < BM * (F / 4); i += 256) {
        const int r = i >> 5, c = (i & 31) * 4;
        const float4 v = *(const float4*)&Bp[(size_t)(mt * BM + r) * F + c];
        *(float4*)&Bs[r][c] = v;
    }
    if (tid < F)            w2s[tid]     = w2[tid];
    else if (tid < F + BM)  rs[tid - F]  = brew[mt * BM + (tid - F)];
    __syncthreads();

    const int nl = tid >> 3;   // 0..31
    const int mb = tid & 7;    // 0..7

    float dacc[8] = {0.f, 0.f, 0.f, 0.f, 0.f, 0.f, 0.f, 0.f};

#pragma unroll 2
    for (int g0 = 0; g0 < F; g0 += 4) {
        const float4 a  = *(const float4*)&As[nl][g0];
        const float4 wv = *(const float4*)&w2s[g0];
#pragma unroll
        for (int j = 0; j < 8; ++j) {
            const float4 b = *(const float4*)&Bs[mb + 8 * j][g0];
            float d = dacc[j];
            d = fmaf(elu_f(a.x - b.x), wv.x, d);
            d = fmaf(elu_f(a.y - b.y), wv.y, d);
            d = fmaf(elu_f(a.z - b.z), wv.z, d);
            d = fmaf(elu_f(a.w - b.w), wv.w, d);
            dacc[j] = d;
        }
    }

    float sw = 0.f, swr = 0.f;
#pragma unroll
    for (int j = 0; j < 8; ++j) {
        const float dist = fabsf(dacc[j]);
        const float w = 1.0f / (dist + 1e-4f);
        sw += w;
        swr = fmaf(w, rs[mb + 8 * j], swr);
    }

    // reduce across the 8 lanes sharing this n (contiguous lanes, xor-butterfly)
#pragma unroll
    for (int k = 1; k < 8; k <<= 1) {
        sw  += __shfl_xor(sw, k);
        swr += __shfl_xor(swr, k);
    }

    if (mb == 0) {
        const int n = nt * BN + nl;
        partials[((size_t)n * MT + mt) * 2 + 0] = sw;
        partials[((size_t)n * MT + mt) * 2 + 1] = swr;
    }
}

// --- Kernel 3: reduce tile partials, divide ----------------------------------
__global__ __launch_bounds__(256) void finalize_kernel(
    const float* __restrict__ partials, float* __restrict__ out)
{
    const int n = blockIdx.x * 256 + threadIdx.x;
    if (n < NROWS) {
        float sw = 0.f, swr = 0.f;
#pragma unroll
        for (int t = 0; t < MT; ++t) {
            sw  += partials[((size_t)n * MT + t) * 2 + 0];
            swr += partials[((size_t)n * MT + t) * 2 + 1];
        }
        out[n] = swr / sw;
    }
}

extern "C" void kernel_launch(void* const* d_in, const int* in_sizes, int n_in,
                              void* d_out, int out_size, void* d_ws, size_t ws_size,
                              hipStream_t stream)
{
    const float* embeds       = (const float*)d_in[0];  // [2048,128]
    const float* base_embeds  = (const float*)d_in[1];  // [2048,128]
    const float* base_rewards = (const float*)d_in[2];  // [2048]
    const float* W1           = (const float*)d_in[3];  // [128,128] (in,out)
    const float* w2           = (const float*)d_in[4];  // [128,1]
    float* out = (float*)d_out;

    // workspace layout: partials [2048*32*2] | A [2048*128] | B [2048*128]
    float* partials = (float*)d_ws;
    float* A  = partials + (size_t)NROWS * MT * 2;
    float* Bp = A + (size_t)NROWS * F;

    proj_kernel<<<(NROWS + MROWS) / 2, 256, 0, stream>>>(embeds, base_embeds, W1, A, Bp);

    dim3 grid2(NROWS / BN, MROWS / BM);
    pair_kernel<<<grid2, 256, 0, stream>>>(A, Bp, w2, base_rewards, partials);

    finalize_kernel<<<NROWS / 256, 256, 0, stream>>>(partials, out);
}

// Round 2
// 119.334 us; speedup vs baseline: 1.0707x; 1.0707x over previous
//
#include <hip/hip_runtime.h>
#include <hip/hip_bf16.h>

#define F      128
#define NROWS  2048
#define MROWS  2048
#define BN     32          // n-rows per block (pair kernel)
#define BM     32          // m-cols per block
#define MT     (MROWS/BM)  // 64 m-tiles
#define LDP    132         // padded LDS row stride in floats: 16B-aligned, %32==4
#define LOG2E  1.44269504088896340736f
#define LN2    0.69314718055994530942f

// --- Kernel 0: prep w2 variants + sum ---------------------------------------
// wa = w2*ln2  (so max(x*log2e,0)*wa == max(x,0)*w2)
// wb = w2      (exp2 branch), w2sum = sum(w2)
__global__ __launch_bounds__(64) void w2prep_kernel(
    const float* __restrict__ w2, float* __restrict__ wa,
    float* __restrict__ wb, float* __restrict__ w2sum)
{
    const int t = threadIdx.x;  // 0..63
    float s = 0.0f;
#pragma unroll
    for (int k = 0; k < 2; ++k) {
        const int g = t + 64 * k;
        const float v = w2[g];
        wa[g] = v * LN2;
        wb[g] = v;
        s += v;
    }
#pragma unroll
    for (int k = 1; k < 64; k <<= 1) s += __shfl_xor(s, k);
    if (t == 0) *w2sum = s;
}

// --- Kernel 1: A = (embeds @ W1)*log2e, B = (base_embeds @ W1)*log2e --------
__global__ __launch_bounds__(256) void proj_kernel(
    const float* __restrict__ embeds, const float* __restrict__ base,
    const float* __restrict__ W1, float* __restrict__ A, float* __restrict__ Bo)
{
    const int tid = threadIdx.x;
    const int sub = tid >> 7;          // 0/1 row within block
    const int g   = tid & 127;
    const int row = blockIdx.x * 2 + sub;

    __shared__ float xs[2][F];
    {
        const float* src = (row < NROWS) ? &embeds[(size_t)row * F]
                                         : &base[(size_t)(row - NROWS) * F];
        xs[sub][g] = src[g];
    }
    __syncthreads();

    float acc = 0.0f;
#pragma unroll 8
    for (int f = 0; f < F; ++f)
        acc = fmaf(xs[sub][f], W1[f * F + g], acc);

    float* dst = (row < NROWS) ? &A[(size_t)row * F]
                               : &Bo[(size_t)(row - NROWS) * F];
    dst[g] = acc * LOG2E;
}

// --- Kernel 2: per-pair elu-dot, inverse-distance partial sums ---------------
// grid (NROWS/BN, MROWS/BM); 256 threads: nl = tid>>3 (32 rows), m covered by
// (tid&7) + 8*j, j=0..3. Deterministic (no atomics).
// Per element: x'=a'-b' (both pre-scaled by log2e)
//   acc += max(x',0)*wa + exp2(min(x',0))*wb        [wa=w2*ln2, wb=w2]
// final: dot = acc - w2sum;  dist = |dot|
__global__ __launch_bounds__(256) void pair_kernel(
    const float* __restrict__ A, const float* __restrict__ Bp,
    const float* __restrict__ wa, const float* __restrict__ wb,
    const float* __restrict__ w2sum_p, const float* __restrict__ brew,
    float* __restrict__ partials)
{
    __shared__ float As[BN][LDP];
    __shared__ float Bs[BM][LDP];
    __shared__ float was[F];
    __shared__ float wbs[F];
    __shared__ float rs[BM];

    const int tid = threadIdx.x;
    const int nt  = blockIdx.x;
    const int mt  = blockIdx.y;

    // stage A-tile & B-tile: 32 rows x 128 floats each -> 1024 float4 each
    for (int i = tid; i < BN * (F / 4); i += 256) {
        const int r = i >> 5, c = (i & 31) * 4;
        const float4 v = *(const float4*)&A[(size_t)(nt * BN + r) * F + c];
        *(float4*)&As[r][c] = v;
    }
    for (int i = tid; i < BM * (F / 4); i += 256) {
        const int r = i >> 5, c = (i & 31) * 4;
        const float4 v = *(const float4*)&Bp[(size_t)(mt * BM + r) * F + c];
        *(float4*)&Bs[r][c] = v;
    }
    if (tid < F)            was[tid]      = wa[tid];
    else                    wbs[tid - F]  = wb[tid - F];
    if (tid < BM)           rs[tid]       = brew[mt * BM + tid];
    const float w2sum = *w2sum_p;     // uniform
    __syncthreads();

    const int nl = tid >> 3;   // 0..31
    const int mb = tid & 7;    // 0..7

    float acc[4] = {0.f, 0.f, 0.f, 0.f};

#pragma unroll 4
    for (int g0 = 0; g0 < F; g0 += 4) {
        const float4 a  = *(const float4*)&As[nl][g0];
        const float4 va = *(const float4*)&was[g0];
        const float4 vb = *(const float4*)&wbs[g0];
#pragma unroll
        for (int j = 0; j < 4; ++j) {
            const float4 b = *(const float4*)&Bs[mb + 8 * j][g0];
            float d = acc[j];
            float x;
            x = a.x - b.x;
            d = fmaf(fmaxf(x, 0.f), va.x, d);
            d = fmaf(__builtin_amdgcn_exp2f(fminf(x, 0.f)), vb.x, d);
            x = a.y - b.y;
            d = fmaf(fmaxf(x, 0.f), va.y, d);
            d = fmaf(__builtin_amdgcn_exp2f(fminf(x, 0.f)), vb.y, d);
            x = a.z - b.z;
            d = fmaf(fmaxf(x, 0.f), va.z, d);
            d = fmaf(__builtin_amdgcn_exp2f(fminf(x, 0.f)), vb.z, d);
            x = a.w - b.w;
            d = fmaf(fmaxf(x, 0.f), va.w, d);
            d = fmaf(__builtin_amdgcn_exp2f(fminf(x, 0.f)), vb.w, d);
            acc[j] = d;
        }
    }

    float sw = 0.f, swr = 0.f;
#pragma unroll
    for (int j = 0; j < 4; ++j) {
        const float dist = fabsf(acc[j] - w2sum);
        const float w = 1.0f / (dist + 1e-4f);
        sw += w;
        swr = fmaf(w, rs[mb + 8 * j], swr);
    }

    // reduce across the 8 lanes sharing this n
#pragma unroll
    for (int k = 1; k < 8; k <<= 1) {
        sw  += __shfl_xor(sw, k);
        swr += __shfl_xor(swr, k);
    }

    if (mb == 0) {
        const int n = nt * BN + nl;
        partials[((size_t)n * MT + mt) * 2 + 0] = sw;
        partials[((size_t)n * MT + mt) * 2 + 1] = swr;
    }
}

// --- Kernel 3: reduce tile partials, divide ----------------------------------
__global__ __launch_bounds__(256) void finalize_kernel(
    const float* __restrict__ partials, float* __restrict__ out)
{
    const int n = blockIdx.x * 256 + threadIdx.x;
    if (n < NROWS) {
        float sw = 0.f, swr = 0.f;
#pragma unroll
        for (int t = 0; t < MT; ++t) {
            sw  += partials[((size_t)n * MT + t) * 2 + 0];
            swr += partials[((size_t)n * MT + t) * 2 + 1];
        }
        out[n] = swr / sw;
    }
}

extern "C" void kernel_launch(void* const* d_in, const int* in_sizes, int n_in,
                              void* d_out, int out_size, void* d_ws, size_t ws_size,
                              hipStream_t stream)
{
    const float* embeds       = (const float*)d_in[0];  // [2048,128]
    const float* base_embeds  = (const float*)d_in[1];  // [2048,128]
    const float* base_rewards = (const float*)d_in[2];  // [2048]
    const float* W1           = (const float*)d_in[3];  // [128,128] (in,out)
    const float* w2           = (const float*)d_in[4];  // [128,1]
    float* out = (float*)d_out;

    // ws layout: partials [2048*MT*2] | A [2048*128] | B [2048*128] | wa[128] | wb[128] | w2sum[1]
    float* partials = (float*)d_ws;
    float* A   = partials + (size_t)NROWS * MT * 2;
    float* Bp  = A  + (size_t)NROWS * F;
    float* wa  = Bp + (size_t)MROWS * F;
    float* wb  = wa + F;
    float* w2s = wb + F;

    w2prep_kernel<<<1, 64, 0, stream>>>(w2, wa, wb, w2s);
    proj_kernel<<<(NROWS + MROWS) / 2, 256, 0, stream>>>(embeds, base_embeds, W1, A, Bp);

    dim3 grid2(NROWS / BN, MROWS / BM);
    pair_kernel<<<grid2, 256, 0, stream>>>(A, Bp, wa, wb, w2s, base_rewards, partials);

    finalize_kernel<<<NROWS / 256, 256, 0, stream>>>(partials, out);
}

// Round 3
// 96.728 us; speedup vs baseline: 1.3210x; 1.2337x over previous
//
#include <hip/hip_runtime.h>
#include <hip/hip_bf16.h>

#define F      128
#define NROWS  2048
#define MROWS  2048
#define BN     64          // n-rows per pair block
#define BM     64          // m-cols per pair block
#define MT     (MROWS/BM)  // 32 m-tiles
#define GC     32          // g-chunk
#define LDW    34          // LDS row stride in float2 (272B: 2-way max aliasing, 16B aligned)
#define LOG2E  1.44269504088896340736f

// --- Kernel 0: w2sum ----------------------------------------------------------
__global__ __launch_bounds__(64) void w2prep_kernel(
    const float* __restrict__ w2, float* __restrict__ w2sum)
{
    const int t = threadIdx.x;
    float s = w2[t] + w2[t + 64];
#pragma unroll
    for (int k = 1; k < 64; k <<= 1) s += __shfl_xor(s, k);
    if (t == 0) *w2sum = s;
}

// --- Kernel 1: projections + ELU precompute -----------------------------------
// A2[n][g] = (aN+1, exp2(aN*log2e)),  B2[m][g] = (bN, exp2(-bN*log2e))
// where aN = (embeds@W1)[n][g], bN = (base@W1)[m][g]   (natural units)
__global__ __launch_bounds__(256) void proj_kernel(
    const float* __restrict__ embeds, const float* __restrict__ base,
    const float* __restrict__ W1, float2* __restrict__ A2, float2* __restrict__ B2)
{
    const int tid = threadIdx.x;
    const int sub = tid >> 7;          // 0/1 row within block
    const int g   = tid & 127;
    const int row = blockIdx.x * 2 + sub;

    __shared__ float xs[2][F];
    {
        const float* src = (row < NROWS) ? &embeds[(size_t)row * F]
                                         : &base[(size_t)(row - NROWS) * F];
        xs[sub][g] = src[g];
    }
    __syncthreads();

    float acc = 0.0f;
#pragma unroll 8
    for (int f = 0; f < F; ++f)
        acc = fmaf(xs[sub][f], W1[f * F + g], acc);

    if (row < NROWS)
        A2[(size_t)row * F + g] = make_float2(acc + 1.0f,
                                              __builtin_amdgcn_exp2f(acc * LOG2E));
    else
        B2[(size_t)(row - NROWS) * F + g] = make_float2(acc,
                                              __builtin_amdgcn_exp2f(-acc * LOG2E));
}

// --- Kernel 2: pair kernel ------------------------------------------------------
// grid (NROWS/BN, MROWS/BM), 256 threads: tr=tid>>4 (16), tc=tid&15 (16).
// Thread owns rows n = nt*64 + tr*4 + i (i<4), cols m = mt*64 + tc + 16*j (j<4).
// Per element: x1 = a1 - b; t = min(EA*EB, 1); s = max(x1, t); acc += s*w2[g]
// (s = elu(x)+1; the -1 folds into w2sum). 5 VALU, no transcendental.
__global__ __launch_bounds__(256) void pair_kernel(
    const float2* __restrict__ A2, const float2* __restrict__ B2,
    const float* __restrict__ w2, const float* __restrict__ w2sum_p,
    const float* __restrict__ brew, float* __restrict__ partials)
{
    __shared__ float2 As2[BN][LDW];
    __shared__ float2 Bs2[BM][LDW];
    __shared__ float  w2s[F];
    __shared__ float  rs[BM];

    const int tid = threadIdx.x;
    const int nt  = blockIdx.x;
    const int mt  = blockIdx.y;
    const int tr  = tid >> 4;
    const int tc  = tid & 15;

    float acc[4][4];
#pragma unroll
    for (int i = 0; i < 4; ++i)
#pragma unroll
        for (int j = 0; j < 4; ++j) acc[i][j] = 0.0f;

#pragma unroll 1
    for (int ch = 0; ch < F / GC; ++ch) {
        const int gc0 = ch * GC;
        // stage A/B chunks: 64 rows x 16 float4 each
        for (int i = tid; i < BN * (GC / 2); i += 256) {   // 1024 iters / 256
            const int r  = i >> 4;
            const int c2 = (i & 15) * 2;
            const float4 va = *(const float4*)&A2[(size_t)(nt * BN + r) * F + gc0 + c2];
            *(float4*)&As2[r][c2] = va;
            const float4 vb = *(const float4*)&B2[(size_t)(mt * BM + r) * F + gc0 + c2];
            *(float4*)&Bs2[r][c2] = vb;
        }
        if (ch == 0) {
            if (tid < F)                      w2s[tid]       = w2[tid];
            else if (tid < F + BM)            rs[tid - F]    = brew[mt * BM + (tid - F)];
        }
        __syncthreads();

#pragma unroll 4
        for (int g2 = 0; g2 < GC; g2 += 2) {
            float4 av[4], bv[4];
#pragma unroll
            for (int i = 0; i < 4; ++i)
                av[i] = *(const float4*)&As2[tr * 4 + i][g2];
#pragma unroll
            for (int j = 0; j < 4; ++j)
                bv[j] = *(const float4*)&Bs2[tc + 16 * j][g2];
            const float2 wv = *(const float2*)&w2s[gc0 + g2];
#pragma unroll
            for (int i = 0; i < 4; ++i) {
#pragma unroll
                for (int j = 0; j < 4; ++j) {
                    float d = acc[i][j];
                    const float x1a = av[i].x - bv[j].x;
                    const float ta  = fminf(av[i].y * bv[j].y, 1.0f);
                    d = fmaf(fmaxf(x1a, ta), wv.x, d);
                    const float x1b = av[i].z - bv[j].z;
                    const float tb  = fminf(av[i].w * bv[j].w, 1.0f);
                    d = fmaf(fmaxf(x1b, tb), wv.y, d);
                    acc[i][j] = d;
                }
            }
        }
        __syncthreads();
    }

    const float w2sum = *w2sum_p;

#pragma unroll
    for (int i = 0; i < 4; ++i) {
        float sw = 0.0f, swr = 0.0f;
#pragma unroll
        for (int j = 0; j < 4; ++j) {
            const float dist = fabsf(acc[i][j] - w2sum);
            const float w = 1.0f / (dist + 1e-4f);
            sw += w;
            swr = fmaf(w, rs[tc + 16 * j], swr);
        }
#pragma unroll
        for (int k = 1; k < 16; k <<= 1) {
            sw  += __shfl_xor(sw, k);
            swr += __shfl_xor(swr, k);
        }
        if (tc == 0) {
            const int n = nt * BN + tr * 4 + i;
            partials[((size_t)n * MT + mt) * 2 + 0] = sw;
            partials[((size_t)n * MT + mt) * 2 + 1] = swr;
        }
    }
}

// --- Kernel 3: reduce tile partials, divide ------------------------------------
__global__ __launch_bounds__(256) void finalize_kernel(
    const float* __restrict__ partials, float* __restrict__ out)
{
    const int n = blockIdx.x * 256 + threadIdx.x;
    if (n < NROWS) {
        float sw = 0.0f, swr = 0.0f;
#pragma unroll
        for (int t = 0; t < MT; ++t) {
            sw  += partials[((size_t)n * MT + t) * 2 + 0];
            swr += partials[((size_t)n * MT + t) * 2 + 1];
        }
        out[n] = swr / sw;
    }
}

extern "C" void kernel_launch(void* const* d_in, const int* in_sizes, int n_in,
                              void* d_out, int out_size, void* d_ws, size_t ws_size,
                              hipStream_t stream)
{
    const float* embeds       = (const float*)d_in[0];  // [2048,128]
    const float* base_embeds  = (const float*)d_in[1];  // [2048,128]
    const float* base_rewards = (const float*)d_in[2];  // [2048]
    const float* W1           = (const float*)d_in[3];  // [128,128] (in,out)
    const float* w2           = (const float*)d_in[4];  // [128,1]
    float* out = (float*)d_out;

    // ws layout: partials [2048*MT*2] | A2 [2048*128 f2] | B2 [2048*128 f2] | w2sum[1]
    float*  partials = (float*)d_ws;
    float2* A2  = (float2*)(partials + (size_t)NROWS * MT * 2);
    float2* B2  = A2 + (size_t)NROWS * F;
    float*  w2s = (float*)(B2 + (size_t)MROWS * F);

    w2prep_kernel<<<1, 64, 0, stream>>>(w2, w2s);
    proj_kernel<<<(NROWS + MROWS) / 2, 256, 0, stream>>>(embeds, base_embeds, W1, A2, B2);

    dim3 grid2(NROWS / BN, MROWS / BM);
    pair_kernel<<<grid2, 256, 0, stream>>>(A2, B2, w2, w2s, base_rewards, partials);

    finalize_kernel<<<(NROWS + 255) / 256, 256, 0, stream>>>(partials, out);
}

// Round 4
// 80.041 us; speedup vs baseline: 1.5964x; 1.2085x over previous
//
#include <hip/hip_runtime.h>
#include <hip/hip_bf16.h>

#define F      128
#define NROWS  2048
#define MROWS  2048
#define BN     128         // n-rows per pair block
#define BM     64          // m-cols per pair block
#define MT     (MROWS/BM)  // 32 m-tiles
#define GC     32          // g-chunk
#define NCH    (F/GC)      // 4 chunks
#define LDS_W  36          // padded LDS row stride (floats): 16B-aligned, %32==4
#define LOG2E  1.44269504088896340736f

typedef float f32x2 __attribute__((ext_vector_type(2)));
typedef float f32x4 __attribute__((ext_vector_type(4)));

__device__ __forceinline__ f32x2 lo2(f32x4 v) { return __builtin_shufflevector(v, v, 0, 1); }
__device__ __forceinline__ f32x2 hi2(f32x4 v) { return __builtin_shufflevector(v, v, 2, 3); }

// --- Kernel 1: projections + ELU precompute + w2sum -------------------------
// A1[n][g] = aN+1            AE[n][g] = exp2(aN*log2e)
// B1[m][g] = -bN             BE[m][g] = exp2(-bN*log2e)
// so x+1 = A1+B1 and exp(x) = AE*BE for x = aN-bN.
__global__ __launch_bounds__(256) void proj_kernel(
    const float* __restrict__ embeds, const float* __restrict__ base,
    const float* __restrict__ W1, const float* __restrict__ w2,
    float* __restrict__ A1, float* __restrict__ AE,
    float* __restrict__ B1, float* __restrict__ BE,
    float* __restrict__ w2sum)
{
    const int tid = threadIdx.x;
    const int sub = tid >> 7;
    const int g   = tid & 127;
    const int row = blockIdx.x * 2 + sub;

    __shared__ float xs[2][F];
    {
        const float* src = (row < NROWS) ? &embeds[(size_t)row * F]
                                         : &base[(size_t)(row - NROWS) * F];
        xs[sub][g] = src[g];
    }
    __syncthreads();

    float acc = 0.0f;
#pragma unroll 8
    for (int f = 0; f < F; ++f)
        acc = fmaf(xs[sub][f], W1[f * F + g], acc);

    if (row < NROWS) {
        const size_t idx = (size_t)row * F + g;
        A1[idx] = acc + 1.0f;
        AE[idx] = __builtin_amdgcn_exp2f(acc * LOG2E);
    } else {
        const size_t idx = (size_t)(row - NROWS) * F + g;
        B1[idx] = -acc;
        BE[idx] = __builtin_amdgcn_exp2f(-acc * LOG2E);
    }

    if (blockIdx.x == 0 && tid < 64) {
        float s = w2[tid] + w2[tid + 64];
#pragma unroll
        for (int k = 1; k < 64; k <<= 1) s += __shfl_xor(s, k);
        if (tid == 0) *w2sum = s;
    }
}

// --- Kernel 2: pair kernel ----------------------------------------------------
// grid (NROWS/BN, MROWS/BM), 256 threads: tr=tid>>4 (16), tc=tid&15 (16).
// Thread owns rows n = nt*128 + tr + 16*i (i<8), cols m = mt*64 + tc + 16*j (j<4).
// Per 2 elems: pk_add (x1=a1+(-b)), pk_mul (e=EA*BE), 2x v_med3, pk_fma.
__global__ __launch_bounds__(256) void pair_kernel(
    const float* __restrict__ A1, const float* __restrict__ AE,
    const float* __restrict__ B1, const float* __restrict__ BE,
    const float* __restrict__ w2, const float* __restrict__ w2sum_p,
    const float* __restrict__ brew, float* __restrict__ partials)
{
    __shared__ float As1[BN][LDS_W], AsE[BN][LDS_W];
    __shared__ float Bs1[BM][LDS_W], BsE[BM][LDS_W];
    __shared__ float w2s[F];
    __shared__ float rs[BM];

    const int tid = threadIdx.x;
    const int nt  = blockIdx.x;
    const int mt  = blockIdx.y;
    const int tr  = tid >> 4;
    const int tc  = tid & 15;

    f32x2 acc2[8][4];
#pragma unroll
    for (int i = 0; i < 8; ++i)
#pragma unroll
        for (int j = 0; j < 4; ++j) acc2[i][j] = (f32x2)(0.0f);

    if (tid < F)                 w2s[tid]     = w2[tid];
    else if (tid < F + BM)       rs[tid - F]  = brew[mt * BM + (tid - F)];

#pragma unroll 1
    for (int ch = 0; ch < NCH; ++ch) {
        const int g0 = ch * GC;
        // stage A planes: 2 x 128 rows x 8 float4 = 2048 vec loads
        for (int i = tid; i < 2048; i += 256) {
            const int pl = i >> 10, r = (i >> 3) & 127, c = (i & 7) * 4;
            const float* src = pl ? AE : A1;
            float* dst = pl ? &AsE[r][c] : &As1[r][c];
            *(f32x4*)dst = *(const f32x4*)&src[(size_t)(nt * BN + r) * F + g0 + c];
        }
        // stage B planes: 2 x 64 rows x 8 float4 = 1024 vec loads
        for (int i = tid; i < 1024; i += 256) {
            const int pl = i >> 9, r = (i >> 3) & 63, c = (i & 7) * 4;
            const float* src = pl ? BE : B1;
            float* dst = pl ? &BsE[r][c] : &Bs1[r][c];
            *(f32x4*)dst = *(const f32x4*)&src[(size_t)(mt * BM + r) * F + g0 + c];
        }
        __syncthreads();

#pragma unroll
        for (int g4 = 0; g4 < GC; g4 += 4) {
            const f32x2 w01 = *(const f32x2*)&w2s[g0 + g4];
            const f32x2 w23 = *(const f32x2*)&w2s[g0 + g4 + 2];
            f32x4 b1v[4], bev[4];
#pragma unroll
            for (int j = 0; j < 4; ++j) {
                b1v[j] = *(const f32x4*)&Bs1[tc + 16 * j][g4];
                bev[j] = *(const f32x4*)&BsE[tc + 16 * j][g4];
            }
#pragma unroll
            for (int i = 0; i < 8; ++i) {
                const f32x4 a1v = *(const f32x4*)&As1[tr + 16 * i][g4];
                const f32x4 aev = *(const f32x4*)&AsE[tr + 16 * i][g4];
                const f32x2 a1lo = lo2(a1v), a1hi = hi2(a1v);
                const f32x2 aelo = lo2(aev), aehi = hi2(aev);
#pragma unroll
                for (int j = 0; j < 4; ++j) {
                    f32x2 x1 = a1lo + lo2(b1v[j]);
                    f32x2 ee = aelo * lo2(bev[j]);
                    f32x2 s;
                    s.x = __builtin_amdgcn_fmed3f(x1.x, ee.x, 1.0f);
                    s.y = __builtin_amdgcn_fmed3f(x1.y, ee.y, 1.0f);
                    acc2[i][j] += s * w01;
                    f32x2 x2 = a1hi + hi2(b1v[j]);
                    f32x2 e2 = aehi * hi2(bev[j]);
                    f32x2 s2;
                    s2.x = __builtin_amdgcn_fmed3f(x2.x, e2.x, 1.0f);
                    s2.y = __builtin_amdgcn_fmed3f(x2.y, e2.y, 1.0f);
                    acc2[i][j] += s2 * w23;
                }
            }
        }
        __syncthreads();
    }

    const float w2sum = *w2sum_p;

#pragma unroll
    for (int i = 0; i < 8; ++i) {
        float sw = 0.0f, swr = 0.0f;
#pragma unroll
        for (int j = 0; j < 4; ++j) {
            const float tot  = acc2[i][j].x + acc2[i][j].y;
            const float dist = fabsf(tot - w2sum);
            const float w = 1.0f / (dist + 1e-4f);
            sw += w;
            swr = fmaf(w, rs[tc + 16 * j], swr);
        }
#pragma unroll
        for (int k = 1; k < 16; k <<= 1) {
            sw  += __shfl_xor(sw, k);
            swr += __shfl_xor(swr, k);
        }
        if (tc == 0) {
            const int n = nt * BN + tr + 16 * i;
            partials[((size_t)n * MT + mt) * 2 + 0] = sw;
            partials[((size_t)n * MT + mt) * 2 + 1] = swr;
        }
    }
}

// --- Kernel 3: reduce tile partials, divide ------------------------------------
__global__ __launch_bounds__(256) void finalize_kernel(
    const float* __restrict__ partials, float* __restrict__ out)
{
    const int n = blockIdx.x * 256 + threadIdx.x;
    if (n < NROWS) {
        float sw = 0.0f, swr = 0.0f;
#pragma unroll
        for (int t = 0; t < MT; ++t) {
            sw  += partials[((size_t)n * MT + t) * 2 + 0];
            swr += partials[((size_t)n * MT + t) * 2 + 1];
        }
        out[n] = swr / sw;
    }
}

extern "C" void kernel_launch(void* const* d_in, const int* in_sizes, int n_in,
                              void* d_out, int out_size, void* d_ws, size_t ws_size,
                              hipStream_t stream)
{
    const float* embeds       = (const float*)d_in[0];  // [2048,128]
    const float* base_embeds  = (const float*)d_in[1];  // [2048,128]
    const float* base_rewards = (const float*)d_in[2];  // [2048]
    const float* W1           = (const float*)d_in[3];  // [128,128] (in,out)
    const float* w2           = (const float*)d_in[4];  // [128,1]
    float* out = (float*)d_out;

    // ws: partials [2048*MT*2] | A1 | AE | B1 | BE (each 2048*128) | w2sum[1]
    float* partials = (float*)d_ws;
    float* A1  = partials + (size_t)NROWS * MT * 2;
    float* AE  = A1 + (size_t)NROWS * F;
    float* B1  = AE + (size_t)NROWS * F;
    float* BE  = B1 + (size_t)MROWS * F;
    float* w2s = BE + (size_t)MROWS * F;

    proj_kernel<<<(NROWS + MROWS) / 2, 256, 0, stream>>>(
        embeds, base_embeds, W1, w2, A1, AE, B1, BE, w2s);

    dim3 grid2(NROWS / BN, MROWS / BM);
    pair_kernel<<<grid2, 256, 0, stream>>>(A1, AE, B1, BE, w2, w2s, base_rewards, partials);

    finalize_kernel<<<(NROWS + 255) / 256, 256, 0, stream>>>(partials, out);
}